// Round 1
// baseline (185.383 us; speedup 1.0000x reference)
//
#include <hip/hip_runtime.h>

#define SDIM 4096
#define ALPHA 0.01f
#define WS_LOG 8                      // 64 per-block log partials at [8..72)
#define WS_ARR 128                    // gathered column arrays
#define WS_PART (WS_ARR + 5 * SDIM)   // per-block reduce partials
#define NRED 2048                     // reduce-role blocks

// ws layout (floats):
//   [8..72)                       64 per-block log partials (k_gather)
//   [128 .. 128+5*4096)           c0 | c1 | c3 | u0 | u1
//                                 (u0/u1 = target cols 0/1 SHIFTED +1:
//                                  u0[i] = tgt[(i-1)&4095][0] — absorbs the
//                                  out+1 misalignment so cost stores are
//                                  aligned float4)
//   [WS_PART .. +2048)            per-block sum_sq partials (reduce role)
//   [WS_PART+2048 .. +4096)       per-block sum3 partials   (reduce role)

// ---------------------------------------------------------------------------
// Kernel 1: gather columns (with +1 shift on target cols), log partials.
// ---------------------------------------------------------------------------
__global__ void k_gather(const float* __restrict__ inp, const float* __restrict__ tgt,
                         float* __restrict__ ws) {
    int n = blockIdx.x * 64 + threadIdx.x;  // 0..4095
    const float* row  = inp + (size_t)n * SDIM;
    const float* trow = tgt + (size_t)n * SDIM;
    float* arr = ws + WS_ARR;

    float v0 = row[0], v1 = row[1], v3 = row[3], v4 = row[4];
    arr[n]            = v0;            // c0
    arr[SDIM + n]     = v1;            // c1
    arr[2 * SDIM + n] = v3;            // c3
    int ns = (n + 1) & (SDIM - 1);     // shifted slot
    arr[3 * SDIM + ns] = trow[0];      // u0[i] = t0[i-1]
    arr[4 * SDIM + ns] = trow[1];      // u1[i] = t1[i-1]

    float lg = logf(v4);
    #pragma unroll
    for (int off = 32; off > 0; off >>= 1) lg += __shfl_down(lg, off);
    if (threadIdx.x == 0) ws[WS_LOG + blockIdx.x] = lg;
}

// ---------------------------------------------------------------------------
// Kernel 2: block-role-specialized fused kernel, 6144 blocks x 256 threads.
//   bid%3==0 (2048 blocks): pure streaming reduction over inp/tgt (128 MB
//                           reads, no stores in hot path -> clean MLP/TLP).
//   bid%3!=0 (4096 blocks): pure cost write. Block n owns the ALIGNED linear
//                           range out[n*4096 .. n*4096+4096); element 0 of
//                           that range is cost[n-1][4095] (row-shifted), all
//                           stores are aligned float4. Only L2-hot reads.
// ---------------------------------------------------------------------------
__global__ void __launch_bounds__(256) k_fused(const float* __restrict__ inp,
                                               const float* __restrict__ tgt,
                                               const float* __restrict__ ws,
                                               float* __restrict__ out,
                                               float* __restrict__ wpart) {
    __shared__ float s1[4], s2[4];
    int bid = blockIdx.x;
    int t = threadIdx.x;
    const float* c0 = ws + WS_ARR;

    if (bid % 3 == 0) {
        // ---- reduce role: sum_sq = sum (inp-tgt)^2, sum3 = sum (c3[col]-tgt)^2
        int r = bid / 3;                               // 0..2047
        const float4* inp4 = (const float4*)inp;
        const float4* tgt4 = (const float4*)tgt;
        const float4* c34  = (const float4*)(c0 + 2 * SDIM);
        int base = r * 256 + t;                        // 0..524287 (float4 idx)
        float a1 = 0.f, a2 = 0.f, b1 = 0.f, b2 = 0.f;
        #pragma unroll
        for (int i = 0; i < 8; i += 2) {
            int ua = base + i * 524288;
            int ub = ua + 524288;
            float4 ia = inp4[ua], ta = tgt4[ua], ca = c34[ua & 1023];
            float4 ib = inp4[ub], tb = tgt4[ub], cb = c34[ub & 1023];
            float d;
            d = ia.x - ta.x; a1 += d * d;  d = ia.y - ta.y; a1 += d * d;
            d = ia.z - ta.z; a1 += d * d;  d = ia.w - ta.w; a1 += d * d;
            d = ca.x - ta.x; a2 += d * d;  d = ca.y - ta.y; a2 += d * d;
            d = ca.z - ta.z; a2 += d * d;  d = ca.w - ta.w; a2 += d * d;
            d = ib.x - tb.x; b1 += d * d;  d = ib.y - tb.y; b1 += d * d;
            d = ib.z - tb.z; b1 += d * d;  d = ib.w - tb.w; b1 += d * d;
            d = cb.x - tb.x; b2 += d * d;  d = cb.y - tb.y; b2 += d * d;
            d = cb.z - tb.z; b2 += d * d;  d = cb.w - tb.w; b2 += d * d;
        }
        a1 += b1; a2 += b2;
        #pragma unroll
        for (int off = 32; off > 0; off >>= 1) {
            a1 += __shfl_down(a1, off);
            a2 += __shfl_down(a2, off);
        }
        int wave = t >> 6;
        if ((t & 63) == 0) { s1[wave] = a1; s2[wave] = a2; }
        __syncthreads();
        if (t == 0) {
            wpart[r]        = s1[0] + s1[1] + s1[2] + s1[3];
            wpart[NRED + r] = s2[0] + s2[1] + s2[2] + s2[3];
        }
    } else {
        // ---- cost-writer role ----
        int n = 2 * (bid / 3) + (bid % 3) - 1;         // 0..4095
        const float* c1 = c0 + SDIM;
        const float4* u04 = (const float4*)(c0 + 3 * SDIM);
        const float4* u14 = (const float4*)(c0 + 4 * SDIM);
        float a0 = c0[n], b0 = c1[n];                  // wave-uniform
        float4* orow4 = (float4*)(out + (size_t)n * SDIM);
        #pragma unroll
        for (int k = 0; k < 4; ++k) {
            int j = k * 256 + t;
            float4 U0 = u04[j], U1 = u14[j];           // L2-hot, aligned
            float e0, e1;
            float4 v;
            e0 = a0 - U0.x; e1 = b0 - U1.x; v.x = 0.5f * (e0 * e0 + e1 * e1);
            e0 = a0 - U0.y; e1 = b0 - U1.y; v.y = 0.5f * (e0 * e0 + e1 * e1);
            e0 = a0 - U0.z; e1 = b0 - U1.z; v.z = 0.5f * (e0 * e0 + e1 * e1);
            e0 = a0 - U0.w; e1 = b0 - U1.w; v.w = 0.5f * (e0 * e0 + e1 * e1);
            if (j == 0) {
                if (n == 0) {
                    v.x = 0.0f;                        // loss slot; k_final overwrites
                } else {
                    float ap = c0[n - 1], bp = c1[n - 1];
                    e0 = ap - U0.x; e1 = bp - U1.x;    // U0.x = t0[4095]
                    v.x = 0.5f * (e0 * e0 + e1 * e1);  // = cost[n-1][4095]
                }
            }
            orow4[j] = v;                              // aligned float4 store
        }
        if (n == SDIM - 1 && t == 255) {
            // tail: out[16M] = cost[4095][4095]
            const float* u0 = c0 + 3 * SDIM;
            const float* u1 = c0 + 4 * SDIM;
            float e0 = a0 - u0[0], e1 = b0 - u1[0];    // u0[0] = t0[4095]
            out[(size_t)SDIM * SDIM] = 0.5f * (e0 * e0 + e1 * e1);
        }
    }
}

// ---------------------------------------------------------------------------
// Kernel 3: reduce 2048+2048 partials + 64 log partials, emit loss.
//   loss = ALPHA * sum_sq - S * sum_log + sum3 / (S*S)
// ---------------------------------------------------------------------------
__global__ void k_final(const float* __restrict__ ws, float* __restrict__ out) {
    __shared__ float s1[4], s2[4];
    float a1 = 0.0f, a2 = 0.0f;
    const float* wpart = ws + WS_PART;
    for (int i = threadIdx.x; i < NRED; i += 256) {
        a1 += wpart[i];
        a2 += wpart[NRED + i];
    }
    #pragma unroll
    for (int off = 32; off > 0; off >>= 1) {
        a1 += __shfl_down(a1, off);
        a2 += __shfl_down(a2, off);
    }
    int wave = threadIdx.x >> 6;
    if ((threadIdx.x & 63) == 0) { s1[wave] = a1; s2[wave] = a2; }
    __syncthreads();
    if (threadIdx.x == 0) {
        float sum_sq = s1[0] + s1[1] + s1[2] + s1[3];
        float sum3   = s2[0] + s2[1] + s2[2] + s2[3];
        float slog = 0.0f;
        #pragma unroll
        for (int i = 0; i < 64; ++i) slog += ws[WS_LOG + i];
        out[0] = ALPHA * sum_sq - (float)SDIM * slog
               + sum3 * (1.0f / ((float)SDIM * (float)SDIM));
    }
}

extern "C" void kernel_launch(void* const* d_in, const int* in_sizes, int n_in,
                              void* d_out, int out_size, void* d_ws, size_t ws_size,
                              hipStream_t stream) {
    const float* inp = (const float*)d_in[0];
    const float* tgt = (const float*)d_in[1];
    float* out = (float*)d_out;
    float* ws  = (float*)d_ws;

    k_gather<<<64, 64, 0, stream>>>(inp, tgt, ws);
    k_fused<<<6144, 256, 0, stream>>>(inp, tgt, ws, out, ws + WS_PART);
    k_final<<<1, 256, 0, stream>>>(ws, out);
}

// Round 3
// 183.073 us; speedup vs baseline: 1.0126x; 1.0126x over previous
//
#include <hip/hip_runtime.h>

#define SDIM 4096
#define ALPHA 0.01f
#define WS_LOG 8                      // 64 per-block log partials at [8..72)
#define WS_ARR 128                    // gathered column arrays
#define WS_PART (WS_ARR + 5 * SDIM)   // per-block reduce partials
#define NRED 2048                     // reduce-role blocks
#define CHUNK 524288                  // float4 stride between pipeline groups

using nfloat4 = __attribute__((ext_vector_type(4))) float;  // native vec for nt-store

// ws layout (floats):
//   [8..72)                       64 per-block log partials (k_gather)
//   [128 .. 128+5*4096)           c0 | c1 | c3 | u0 | u1
//                                 (u0/u1 = target cols 0/1 SHIFTED +1 so the
//                                  out+1 misalignment becomes aligned float4)
//   [WS_PART .. +2048)            per-block sum_sq partials (reduce role)
//   [WS_PART+2048 .. +4096)       per-block sum3 partials   (reduce role)

// ---------------------------------------------------------------------------
// Kernel 1: gather columns (with +1 shift on target cols), log partials.
// ---------------------------------------------------------------------------
__global__ void k_gather(const float* __restrict__ inp, const float* __restrict__ tgt,
                         float* __restrict__ ws) {
    int n = blockIdx.x * 64 + threadIdx.x;  // 0..4095
    const float* row  = inp + (size_t)n * SDIM;
    const float* trow = tgt + (size_t)n * SDIM;
    float* arr = ws + WS_ARR;

    float v0 = row[0], v1 = row[1], v3 = row[3], v4 = row[4];
    arr[n]            = v0;            // c0
    arr[SDIM + n]     = v1;            // c1
    arr[2 * SDIM + n] = v3;            // c3
    int ns = (n + 1) & (SDIM - 1);     // shifted slot
    arr[3 * SDIM + ns] = trow[0];      // u0[i] = t0[i-1]
    arr[4 * SDIM + ns] = trow[1];      // u1[i] = t1[i-1]

    float lg = logf(v4);
    #pragma unroll
    for (int off = 32; off > 0; off >>= 1) lg += __shfl_down(lg, off);
    if (threadIdx.x == 0) ws[WS_LOG + blockIdx.x] = lg;
}

// ---------------------------------------------------------------------------
// Kernel 2: role-specialized fused kernel, 6144 blocks x 256 threads.
//   bid%3==0 (2048): streaming reduction, hand-pipelined depth-3 (≈6 KB of
//                    loads in flight per wave) to fix the MLP starvation the
//                    compiler's min-VGPR schedule produced (VGPR 32 -> ~56).
//   bid%3!=0 (4096): cost writer. Aligned float4 NONTEMPORAL stores so the
//                    64 MB out stream does not write-allocate L2/L3 and evict
//                    the inp/tgt read set between iterations.
// ---------------------------------------------------------------------------

#define LOADG(g) \
    float4 A##g = inp4[base + (g) * CHUNK]; \
    float4 B##g = tgt4[base + (g) * CHUNK];

#define ACCG(g) { \
    float d; \
    d = A##g.x - B##g.x; a1 += d * d;  d = A##g.y - B##g.y; a1 += d * d; \
    d = A##g.z - B##g.z; a1 += d * d;  d = A##g.w - B##g.w; a1 += d * d; \
    d = ca.x  - B##g.x; a2 += d * d;   d = ca.y  - B##g.y; a2 += d * d; \
    d = ca.z  - B##g.z; a2 += d * d;   d = ca.w  - B##g.w; a2 += d * d; }

__global__ void __launch_bounds__(256) k_fused(const float* __restrict__ inp,
                                               const float* __restrict__ tgt,
                                               const float* __restrict__ ws,
                                               float* __restrict__ out,
                                               float* __restrict__ wpart) {
    __shared__ float s1[4], s2[4];
    int bid = blockIdx.x;
    int t = threadIdx.x;
    const float* c0 = ws + WS_ARR;

    if (bid % 3 == 0) {
        // ---- reduce role: sum_sq = sum (inp-tgt)^2, sum3 = sum (c3[col]-tgt)^2
        int r = bid / 3;                               // 0..2047
        const float4* inp4 = (const float4*)inp;
        const float4* tgt4 = (const float4*)tgt;
        const float4* c34  = (const float4*)(c0 + 2 * SDIM);
        int base = r * 256 + t;                        // 0..524287 (float4 idx)
        // (base + g*CHUNK) & 1023 == base & 1023 -> c3 fragment is loop-invariant
        float4 ca = c34[base & 1023];
        float a1 = 0.f, a2 = 0.f;

        // depth-3 software pipeline: ~6 wave-loads outstanding at all times
        LOADG(0) LOADG(1) LOADG(2)
        ACCG(0)  LOADG(3)
        ACCG(1)  LOADG(4)
        ACCG(2)  LOADG(5)
        ACCG(3)  LOADG(6)
        ACCG(4)  LOADG(7)
        ACCG(5)  ACCG(6)  ACCG(7)

        #pragma unroll
        for (int off = 32; off > 0; off >>= 1) {
            a1 += __shfl_down(a1, off);
            a2 += __shfl_down(a2, off);
        }
        int wave = t >> 6;
        if ((t & 63) == 0) { s1[wave] = a1; s2[wave] = a2; }
        __syncthreads();
        if (t == 0) {
            wpart[r]        = s1[0] + s1[1] + s1[2] + s1[3];
            wpart[NRED + r] = s2[0] + s2[1] + s2[2] + s2[3];
        }
    } else {
        // ---- cost-writer role: block n owns aligned range out[n*4096 ..) ----
        int n = 2 * (bid / 3) + (bid % 3) - 1;         // 0..4095
        const float* c1 = c0 + SDIM;
        const float4* u04 = (const float4*)(c0 + 3 * SDIM);
        const float4* u14 = (const float4*)(c0 + 4 * SDIM);
        float a0 = c0[n], b0 = c1[n];                  // wave-uniform

        // hoist the 8 L2-hot loads
        float4 U0[4], U1[4];
        #pragma unroll
        for (int k = 0; k < 4; ++k) {
            U0[k] = u04[k * 256 + t];
            U1[k] = u14[k * 256 + t];
        }

        nfloat4* orow4 = (nfloat4*)(out + (size_t)n * SDIM);
        #pragma unroll
        for (int k = 0; k < 4; ++k) {
            int j = k * 256 + t;
            float e0, e1;
            nfloat4 v;
            e0 = a0 - U0[k].x; e1 = b0 - U1[k].x; v.x = 0.5f * (e0 * e0 + e1 * e1);
            e0 = a0 - U0[k].y; e1 = b0 - U1[k].y; v.y = 0.5f * (e0 * e0 + e1 * e1);
            e0 = a0 - U0[k].z; e1 = b0 - U1[k].z; v.z = 0.5f * (e0 * e0 + e1 * e1);
            e0 = a0 - U0[k].w; e1 = b0 - U1[k].w; v.w = 0.5f * (e0 * e0 + e1 * e1);
            if (j == 0) {
                if (n == 0) {
                    v.x = 0.0f;                        // loss slot; k_final overwrites
                } else {
                    float ap = c0[n - 1], bp = c1[n - 1];
                    e0 = ap - U0[0].x; e1 = bp - U1[0].x;  // U0[0].x = t0[4095]
                    v.x = 0.5f * (e0 * e0 + e1 * e1);      // = cost[n-1][4095]
                }
            }
            __builtin_nontemporal_store(v, &orow4[j]);     // no L2/L3 allocate
        }
        if (n == SDIM - 1 && t == 255) {
            // tail: out[16M] = cost[4095][4095]
            const float* u0 = c0 + 3 * SDIM;
            const float* u1 = c0 + 4 * SDIM;
            float e0 = a0 - u0[0], e1 = b0 - u1[0];    // u0[0] = t0[4095]
            out[(size_t)SDIM * SDIM] = 0.5f * (e0 * e0 + e1 * e1);
        }
    }
}

// ---------------------------------------------------------------------------
// Kernel 3: reduce 2048+2048 partials + 64 log partials, emit loss.
//   loss = ALPHA * sum_sq - S * sum_log + sum3 / (S*S)
// ---------------------------------------------------------------------------
__global__ void k_final(const float* __restrict__ ws, float* __restrict__ out) {
    __shared__ float s1[4], s2[4];
    float a1 = 0.0f, a2 = 0.0f;
    const float* wpart = ws + WS_PART;
    for (int i = threadIdx.x; i < NRED; i += 256) {
        a1 += wpart[i];
        a2 += wpart[NRED + i];
    }
    #pragma unroll
    for (int off = 32; off > 0; off >>= 1) {
        a1 += __shfl_down(a1, off);
        a2 += __shfl_down(a2, off);
    }
    int wave = threadIdx.x >> 6;
    if ((threadIdx.x & 63) == 0) { s1[wave] = a1; s2[wave] = a2; }
    __syncthreads();
    if (threadIdx.x == 0) {
        float sum_sq = s1[0] + s1[1] + s1[2] + s1[3];
        float sum3   = s2[0] + s2[1] + s2[2] + s2[3];
        float slog = 0.0f;
        #pragma unroll
        for (int i = 0; i < 64; ++i) slog += ws[WS_LOG + i];
        out[0] = ALPHA * sum_sq - (float)SDIM * slog
               + sum3 * (1.0f / ((float)SDIM * (float)SDIM));
    }
}

extern "C" void kernel_launch(void* const* d_in, const int* in_sizes, int n_in,
                              void* d_out, int out_size, void* d_ws, size_t ws_size,
                              hipStream_t stream) {
    const float* inp = (const float*)d_in[0];
    const float* tgt = (const float*)d_in[1];
    float* out = (float*)d_out;
    float* ws  = (float*)d_ws;

    k_gather<<<64, 64, 0, stream>>>(inp, tgt, ws);
    k_fused<<<6144, 256, 0, stream>>>(inp, tgt, ws, out, ws + WS_PART);
    k_final<<<1, 256, 0, stream>>>(ws, out);
}

// Round 4
// 177.530 us; speedup vs baseline: 1.0442x; 1.0312x over previous
//
#include <hip/hip_runtime.h>

#define SDIM 4096
#define ALPHA 0.01f
#define WS_LOG 8                      // 64 per-block log partials at [8..72)
#define WS_ARR 128                    // gathered column arrays
#define WS_PART (WS_ARR + 5 * SDIM)   // per-block reduce partials
#define NRED 2048                     // reduce blocks
#define CHUNK 524288                  // float4 stride between reduce groups

using nfloat4 = __attribute__((ext_vector_type(4))) float;  // native vec for nt-store

// ws layout (floats):
//   [8..72)                       64 per-block log partials (k_gather)
//   [128 .. 128+5*4096)           c0 | c1 | c3 | u0 | u1
//                                 (u0/u1 = target cols 0/1 SHIFTED +1 so the
//                                  out+1 misalignment becomes aligned float4)
//   [WS_PART .. +2048)            per-block sum_sq partials (k_reduce)
//   [WS_PART+2048 .. +4096)       per-block sum3 partials   (k_reduce)

// ---------------------------------------------------------------------------
// Kernel 1: gather columns (with +1 shift on target cols), log partials.
// ---------------------------------------------------------------------------
__global__ void k_gather(const float* __restrict__ inp, const float* __restrict__ tgt,
                         float* __restrict__ ws) {
    int n = blockIdx.x * 64 + threadIdx.x;  // 0..4095
    const float* row  = inp + (size_t)n * SDIM;
    const float* trow = tgt + (size_t)n * SDIM;
    float* arr = ws + WS_ARR;

    float v0 = row[0], v1 = row[1], v3 = row[3], v4 = row[4];
    arr[n]            = v0;            // c0
    arr[SDIM + n]     = v1;            // c1
    arr[2 * SDIM + n] = v3;            // c3
    int ns = (n + 1) & (SDIM - 1);     // shifted slot
    arr[3 * SDIM + ns] = trow[0];      // u0[i] = t0[i-1]
    arr[4 * SDIM + ns] = trow[1];      // u1[i] = t1[i-1]

    float lg = logf(v4);
    #pragma unroll
    for (int off = 32; off > 0; off >>= 1) lg += __shfl_down(lg, off);
    if (threadIdx.x == 0) ws[WS_LOG + blockIdx.x] = lg;
}

// ---------------------------------------------------------------------------
// Kernel 2: pure cost writer. 2048 blocks x 256 threads, 2 rows per block
// (exactly one resident round: 8 blocks/CU x 256 CU). Per thread: 8
// independent aligned nontemporal float4 stores. Only L2-hot reads (32 KB).
// Isolating this stream answers: is there a ~1 TB/s write wall?
// ---------------------------------------------------------------------------
__global__ void __launch_bounds__(256) k_write(const float* __restrict__ ws,
                                               float* __restrict__ out) {
    int b = blockIdx.x;                // 0..2047
    int t = threadIdx.x;
    int n0 = 2 * b, n1 = 2 * b + 1;
    const float* c0 = ws + WS_ARR;
    const float* c1 = c0 + SDIM;
    const float4* u04 = (const float4*)(c0 + 3 * SDIM);
    const float4* u14 = (const float4*)(c0 + 4 * SDIM);

    float a00 = c0[n0], b00 = c1[n0];  // wave-uniform scalars
    float a01 = c0[n1], b01 = c1[n1];

    // hoist the 8 L2-hot loads (shared by both rows)
    float4 U0[4], U1[4];
    #pragma unroll
    for (int k = 0; k < 4; ++k) {
        U0[k] = u04[k * 256 + t];
        U1[k] = u14[k * 256 + t];
    }

    nfloat4* orow0 = (nfloat4*)(out + (size_t)n0 * SDIM);
    nfloat4* orow1 = (nfloat4*)(out + (size_t)n1 * SDIM);
    #pragma unroll
    for (int k = 0; k < 4; ++k) {
        int j = k * 256 + t;
        float e0, e1;
        nfloat4 v0, v1;
        e0 = a00 - U0[k].x; e1 = b00 - U1[k].x; v0.x = 0.5f * (e0 * e0 + e1 * e1);
        e0 = a00 - U0[k].y; e1 = b00 - U1[k].y; v0.y = 0.5f * (e0 * e0 + e1 * e1);
        e0 = a00 - U0[k].z; e1 = b00 - U1[k].z; v0.z = 0.5f * (e0 * e0 + e1 * e1);
        e0 = a00 - U0[k].w; e1 = b00 - U1[k].w; v0.w = 0.5f * (e0 * e0 + e1 * e1);
        e0 = a01 - U0[k].x; e1 = b01 - U1[k].x; v1.x = 0.5f * (e0 * e0 + e1 * e1);
        e0 = a01 - U0[k].y; e1 = b01 - U1[k].y; v1.y = 0.5f * (e0 * e0 + e1 * e1);
        e0 = a01 - U0[k].z; e1 = b01 - U1[k].z; v1.z = 0.5f * (e0 * e0 + e1 * e1);
        e0 = a01 - U0[k].w; e1 = b01 - U1[k].w; v1.w = 0.5f * (e0 * e0 + e1 * e1);
        if (j == 0) {
            // element 0 of row-range n is cost[n-1][4095] (shifted layout)
            if (n0 == 0) {
                v0.x = 0.0f;                       // loss slot; k_final overwrites
            } else {
                float ap = c0[n0 - 1], bp = c1[n0 - 1];
                e0 = ap - U0[0].x; e1 = bp - U1[0].x;   // U0[0].x = t0[4095]
                v0.x = 0.5f * (e0 * e0 + e1 * e1);
            }
            // n1 - 1 == n0
            e0 = a00 - U0[0].x; e1 = b00 - U1[0].x;
            v1.x = 0.5f * (e0 * e0 + e1 * e1);
        }
        __builtin_nontemporal_store(v0, &orow0[j]);
        __builtin_nontemporal_store(v1, &orow1[j]);
    }
    if (n1 == SDIM - 1 && t == 255) {
        // tail: out[16M] = cost[4095][4095]
        const float* u0 = c0 + 3 * SDIM;
        const float* u1 = c0 + 4 * SDIM;
        float e0 = a01 - u0[0], e1 = b01 - u1[0];  // u0[0] = t0[4095]
        out[(size_t)SDIM * SDIM] = 0.5f * (e0 * e0 + e1 * e1);
    }
}

// ---------------------------------------------------------------------------
// Kernel 3: pure streaming reduction over inp/tgt (128 MB reads, no stores
// in hot path). m13-style: TLP from 2048 blocks carries the MLP; light
// 2x unroll for FP-chain ILP.
//   sum_sq = sum (inp-tgt)^2, sum3 = sum (c3[col]-tgt)^2
// ---------------------------------------------------------------------------
__global__ void __launch_bounds__(256) k_reduce(const float* __restrict__ inp,
                                                const float* __restrict__ tgt,
                                                const float* __restrict__ ws,
                                                float* __restrict__ wpart) {
    __shared__ float s1[4], s2[4];
    int r = blockIdx.x;                            // 0..2047
    int t = threadIdx.x;
    const float* c0 = ws + WS_ARR;
    const float4* inp4 = (const float4*)inp;
    const float4* tgt4 = (const float4*)tgt;
    const float4* c34  = (const float4*)(c0 + 2 * SDIM);
    int base = r * 256 + t;                        // 0..524287 (float4 idx)
    // (base + g*CHUNK) & 1023 == base & 1023 -> c3 fragment loop-invariant
    float4 ca = c34[base & 1023];
    float a1 = 0.f, a2 = 0.f, b1 = 0.f, b2 = 0.f;

    #pragma unroll
    for (int g = 0; g < 8; g += 2) {
        int ua = base + g * CHUNK;
        int ub = ua + CHUNK;
        float4 ia = inp4[ua], ta = tgt4[ua];
        float4 ib = inp4[ub], tb = tgt4[ub];
        float d;
        d = ia.x - ta.x; a1 += d * d;  d = ia.y - ta.y; a1 += d * d;
        d = ia.z - ta.z; a1 += d * d;  d = ia.w - ta.w; a1 += d * d;
        d = ca.x - ta.x; a2 += d * d;  d = ca.y - ta.y; a2 += d * d;
        d = ca.z - ta.z; a2 += d * d;  d = ca.w - ta.w; a2 += d * d;
        d = ib.x - tb.x; b1 += d * d;  d = ib.y - tb.y; b1 += d * d;
        d = ib.z - tb.z; b1 += d * d;  d = ib.w - tb.w; b1 += d * d;
        d = ca.x - tb.x; b2 += d * d;  d = ca.y - tb.y; b2 += d * d;
        d = ca.z - tb.z; b2 += d * d;  d = ca.w - tb.w; b2 += d * d;
    }
    a1 += b1; a2 += b2;
    #pragma unroll
    for (int off = 32; off > 0; off >>= 1) {
        a1 += __shfl_down(a1, off);
        a2 += __shfl_down(a2, off);
    }
    int wave = t >> 6;
    if ((t & 63) == 0) { s1[wave] = a1; s2[wave] = a2; }
    __syncthreads();
    if (t == 0) {
        wpart[r]        = s1[0] + s1[1] + s1[2] + s1[3];
        wpart[NRED + r] = s2[0] + s2[1] + s2[2] + s2[3];
    }
}

// ---------------------------------------------------------------------------
// Kernel 4: reduce 2048+2048 partials + 64 log partials, emit loss.
//   loss = ALPHA * sum_sq - S * sum_log + sum3 / (S*S)
// ---------------------------------------------------------------------------
__global__ void k_final(const float* __restrict__ ws, float* __restrict__ out) {
    __shared__ float s1[4], s2[4];
    float a1 = 0.0f, a2 = 0.0f;
    const float* wpart = ws + WS_PART;
    for (int i = threadIdx.x; i < NRED; i += 256) {
        a1 += wpart[i];
        a2 += wpart[NRED + i];
    }
    #pragma unroll
    for (int off = 32; off > 0; off >>= 1) {
        a1 += __shfl_down(a1, off);
        a2 += __shfl_down(a2, off);
    }
    int wave = threadIdx.x >> 6;
    if ((threadIdx.x & 63) == 0) { s1[wave] = a1; s2[wave] = a2; }
    __syncthreads();
    if (threadIdx.x == 0) {
        float sum_sq = s1[0] + s1[1] + s1[2] + s1[3];
        float sum3   = s2[0] + s2[1] + s2[2] + s2[3];
        float slog = 0.0f;
        #pragma unroll
        for (int i = 0; i < 64; ++i) slog += ws[WS_LOG + i];
        out[0] = ALPHA * sum_sq - (float)SDIM * slog
               + sum3 * (1.0f / ((float)SDIM * (float)SDIM));
    }
}

extern "C" void kernel_launch(void* const* d_in, const int* in_sizes, int n_in,
                              void* d_out, int out_size, void* d_ws, size_t ws_size,
                              hipStream_t stream) {
    const float* inp = (const float*)d_in[0];
    const float* tgt = (const float*)d_in[1];
    float* out = (float*)d_out;
    float* ws  = (float*)d_ws;

    k_gather<<<64, 64, 0, stream>>>(inp, tgt, ws);
    k_write<<<NRED, 256, 0, stream>>>(ws, out);
    k_reduce<<<NRED, 256, 0, stream>>>(inp, tgt, ws, ws + WS_PART);
    k_final<<<1, 256, 0, stream>>>(ws, out);
}